// Round 14
// baseline (8465.007 us; speedup 1.0000x reference)
//
#include <hip/hip_runtime.h>
#include <cstdint>

constexpr int B = 32, ET = 1024, DT = 1024, D = 256, PAD = 15, PT = ET + 2*PAD;
constexpr int NT = 32;                 // 32 t-tiles of 32 per batch
constexpr float LOG2E = 1.4426950408889634f;

typedef __attribute__((ext_vector_type(4))) float f32x4;
typedef __attribute__((ext_vector_type(4))) unsigned int uint4v;
typedef __attribute__((ext_vector_type(8))) __bf16 bf16x8;

// ws float layout (double-buffered by step parity; NO atomics, NO barriers)
constexpr size_t PBUF_OFF = 0;                            // [B][2 par][2 ch][PT] ch0=raw, ch1=cum
constexpr size_t PART_OFF = PBUF_OFF + (size_t)B*4*PT;    // [B][2 par][NT][D] raw PV partials
constexpr size_t SSUM_OFF = PART_OFF + (size_t)B*2*NT*D;  // [B][2 par][NT] raw tile sums
constexpr size_t WF_OFF   = SSUM_OFF + (size_t)B*2*NT;    // A-frag table, 16384 floats:
// [16 dtile][2 ch][2 split][64 lane][8 bf16]  (A[d][k]: lane = (d&15) + 16*(k/8), elem = k%8)

__global__ __launch_bounds__(256) void k_init(const float* __restrict__ W,
                                              float* __restrict__ ws) {
  int i0 = blockIdx.x*256 + threadIdx.x;
  int stride = gridDim.x*256;
  for (int i = i0; i < B*4*PT; i += stride) ws[PBUF_OFF + i] = 0.f;
  for (int i = i0; i < B*2*NT*D; i += stride) ws[PART_OFF + i] = 0.f;
  for (int i = i0; i < B*2*NT; i += stride) ws[SSUM_OFF + i] = 1.f/NT;  // Z(step0)=1
  // A-fragment table: hi/lo bf16 (truncation split) of W, zero-padded tap 31
  for (int i = i0; i < 16*2*2*64*8; i += stride) {
    int j = i & 7, lane = (i >> 3) & 63, split = (i >> 9) & 1,
        ch = (i >> 10) & 1, dt = i >> 11;
    int d = dt*16 + (lane & 15);
    int koff = (lane >> 4)*8 + j;
    float val = (koff < 31) ? W[d*62 + ch*31 + koff] : 0.f;
    unsigned bits = __float_as_uint(val);
    unsigned hb = bits & 0xFFFF0000u;
    unsigned half;
    if (split == 0) half = bits >> 16;
    else            half = __float_as_uint(val - __uint_as_float(hb)) >> 16;
    ((unsigned short*)(ws + WF_OFF))[i] = (unsigned short)half;
  }
}

__device__ __forceinline__ f32x4 mfma16(uint4v a, uint4v b, f32x4 c) {
  return __builtin_amdgcn_mfma_f32_16x16x32_bf16(
      __builtin_bit_cast(bf16x8, a), __builtin_bit_cast(bf16x8, b), c, 0, 0, 0);
}

// One decoder step. Reads parity p state (published by step-1), writes parity p^1.
// Kernel boundary provides all cross-block synchronization.
__global__ __attribute__((amdgpu_flat_work_group_size(256, 256), amdgpu_waves_per_eu(2, 4)))
void k_step(
    const float* __restrict__ enc,   // [B][ET][D]
    const float* __restrict__ mel,   // [B][DT][D]
    const int* __restrict__ elen, const int* __restrict__ olen,
    const float* __restrict__ vw,    // [D]
    float* __restrict__ ws,
    float* __restrict__ out_att,     // [B][DT][D]
    float* __restrict__ out_sc,      // [B][DT][ET]
    int step) {
  const int tid = threadIdx.x;
  const int lane = tid & 63;
  const int wq = __builtin_amdgcn_readfirstlane(tid >> 6);  // wave id 0..3
  const int bid = blockIdx.x;
  const int xcd = bid & 7, slot = bid >> 3;                 // slot 0..127
  const int b = ((slot & 3) << 3) | xcd;                    // L2-locality heuristic
  const int tile = slot >> 2;                               // 0..31
  const int t0 = tile * 32;
  const int p = step & 1, np = p ^ 1;

  float* pb = ws + PBUF_OFF + (size_t)b*4*PT;
  const float* raw_p = pb + (size_t)(p*2 + 0)*PT;
  const float* cum_p = pb + (size_t)(p*2 + 1)*PT;
  float* raw_n = pb + (size_t)(np*2 + 0)*PT;
  float* cum_n = pb + (size_t)(np*2 + 1)*PT;
  const float* part_p = ws + PART_OFF + ((size_t)b*2 + p)*NT*D;
  float*       part_n = ws + PART_OFF + ((size_t)b*2 + np)*NT*D;
  const float* S_p = ws + SSUM_OFF + (b*2 + p)*NT;
  float*       S_n = ws + SSUM_OFF + (b*2 + np)*NT;

  __shared__ float s_pa[64], s_pc[64], s_sc[NT], s_z;
  __shared__ __align__(16) float u_lds[256], v_lds[256];
  __shared__ __align__(16) float s_part[NT][20];
  __shared__ __align__(16) float s_ra[4][256];

  const int L = elen[b];
  const int OL = olen[b];

  // ---- issue ALL independent global loads up front (one latency window) ----
  float zv = 0.f;
  if (tid < 32) zv = S_p[tid];
  float rv = 0.f, cv = 0.f;
  if (tid < 64) {
    int ix = t0 + tid; if (ix > PT-1) ix = PT-1;
    rv = raw_p[ix];
    cv = cum_p[ix];
  }
  float usum = 0.f;
  {
    const float* pp = part_p + tid;
#pragma unroll
    for (int j = 0; j < NT; ++j) usum += pp[j*D];
  }
  const float melv = mel[((size_t)b*DT + step)*D + tid];
  v_lds[tid] = vw[tid];

  // cooperative z-reduce (wave 0, lanes 0..31 hold values)
  if (tid < 64) {
#pragma unroll
    for (int m = 1; m < 32; m <<= 1) zv += __shfl_xor(zv, m, 64);
    if (tid == 0) s_z = __builtin_amdgcn_rcpf(zv);
  }
  __syncthreads();

  const float Zinv = s_z;
  // stage conv windows: score = masked raw/Z ; cum = cum_old + score
  if (tid < 64) {
    int ix = t0 + tid;
    float sc = (ix < L + PAD) ? rv * Zinv : 0.f;   // mask AFTER softmax (ref order)
    s_pa[tid] = sc;
    s_pc[tid] = cv + sc;
  }
  usum *= Zinv;                      // att_out(step-1)[d=tid]
  if (tile == 0 && step > 0) {
    float dmp = (step-1 < OL) ? 1.f : 0.f;
    out_att[((size_t)b*DT + step-1)*D + tid] = usum * dmp;
  }
  const float dm = (step < OL) ? 1.f : 0.f;
  u_lds[tid] = fmaf(melv, dm, usum); // u[d=tid]
  __syncthreads();

  // ---- conv via MFMA (split-bf16), then tanh + v-dot epilogue ----
  // B[k][t'] per channel: value = window[t' + k] (k=31 -> 0); lane = t'+16*(k/8), elem = k%8
  uint4v Bf[2][2][2];   // [tt][ch][split]
  {
    const int tq = lane >> 4, tc = lane & 15;
#pragma unroll
    for (int tt = 0; tt < 2; ++tt)
#pragma unroll
      for (int ch = 0; ch < 2; ++ch) {
        const float* src = ch ? s_pc : s_pa;
        const int base = tt*16 + tc;
#pragma unroll
        for (int jj = 0; jj < 4; ++jj) {
          unsigned hpair = 0, lpair = 0;
#pragma unroll
          for (int h = 0; h < 2; ++h) {
            int koff = tq*8 + jj*2 + h;
            float x = (koff < 31) ? src[base + koff] : 0.f;
            unsigned bits = __float_as_uint(x);
            unsigned hb = bits & 0xFFFF0000u;
            unsigned lb = __float_as_uint(x - __uint_as_float(hb));
            hpair |= (bits >> 16) << (16*h);
            lpair |= (lb >> 16) << (16*h);
          }
          Bf[tt][ch][0][jj] = hpair;
          Bf[tt][ch][1][jj] = lpair;
        }
      }
  }

  const uint4v* ap = (const uint4v*)(ws + WF_OFF);
  float ep0 = 0.f, ep1 = 0.f;
#pragma unroll
  for (int dti = 0; dti < 4; ++dti) {
    const int dt = wq*4 + dti;      // this wave's d-tile (16 d rows)
    uint4v a0h = ap[((dt*2 + 0)*2 + 0)*64 + lane];   // ch0 hi
    uint4v a0l = ap[((dt*2 + 0)*2 + 1)*64 + lane];   // ch0 lo
    uint4v a1h = ap[((dt*2 + 1)*2 + 0)*64 + lane];   // ch1 hi
    uint4v a1l = ap[((dt*2 + 1)*2 + 1)*64 + lane];   // ch1 lo
    const int du = dt*16 + (lane >> 4)*4;            // C rows this lane holds
    f32x4 u4 = *(const f32x4*)&u_lds[du];
    f32x4 v4 = *(const f32x4*)&v_lds[du];
#pragma unroll
    for (int tt = 0; tt < 2; ++tt) {
      f32x4 acc = {0.f, 0.f, 0.f, 0.f};
      acc = mfma16(a0h, Bf[tt][0][0], acc);   // hi*hi ch0
      acc = mfma16(a0l, Bf[tt][0][0], acc);   // lo*hi ch0
      acc = mfma16(a0h, Bf[tt][0][1], acc);   // hi*lo ch0
      acc = mfma16(a1h, Bf[tt][1][0], acc);   // hi*hi ch1
      acc = mfma16(a1l, Bf[tt][1][0], acc);   // lo*hi ch1
      acc = mfma16(a1h, Bf[tt][1][1], acc);   // hi*lo ch1
      float ep = 0.f;
#pragma unroll
      for (int r = 0; r < 4; ++r) {
        float s = acc[r] + u4[r];
        // v*tanh(s), tanh(s) = 1 - 2/(exp(2s)+1)
        float ex = __builtin_amdgcn_exp2f(s * (2.f*LOG2E));
        float th = fmaf(-2.f, __builtin_amdgcn_rcpf(ex + 1.f), 1.f);
        ep = fmaf(v4[r], th, ep);
      }
      if (tt == 0) ep0 += ep; else ep1 += ep;
    }
  }
  // partial energies: 16 per t (4 waves x 4 row-quads), same reduce as before
  s_part[lane & 15][(wq << 2) | (lane >> 4)] = ep0;
  s_part[16 + (lane & 15)][(wq << 2) | (lane >> 4)] = ep1;
  __syncthreads();

  // ---- energies -> raw exp (NO max-sub: |e| <= sum|v| ~12); publish ----
  if (tid < NT) {
    const float4 r0 = *(const float4*)&s_part[tid][0];
    const float4 r1 = *(const float4*)&s_part[tid][4];
    const float4 r2 = *(const float4*)&s_part[tid][8];
    const float4 r3 = *(const float4*)&s_part[tid][12];
    float e = (((r0.x+r0.y)+(r0.z+r0.w)) + ((r1.x+r1.y)+(r1.z+r1.w)))
            + (((r2.x+r2.y)+(r2.z+r2.w)) + ((r3.x+r3.y)+(r3.z+r3.w)));
    float raw = __builtin_amdgcn_exp2f(e * LOG2E);
    const int t = t0 + tid;
    raw_n[PAD + t] = raw;                         // raw score state
    s_sc[tid] = (t < L) ? raw : 0.f;              // masked raw for PV
    float ts = raw;                               // tile sum over ALL t (denominator)
#pragma unroll
    for (int msk = 1; msk < NT; msk <<= 1) ts += __shfl_xor(ts, msk, 64);
    if (tid == 0) S_n[tile] = ts;
    cum_n[PAD + t] = s_pc[tid + 15];              // cum through step-1 (owner slice)
    if (step > 0)
      out_sc[((size_t)b*DT + step-1)*ET + t] = s_pa[tid + 15];  // delayed score write
  }
  __syncthreads();

  // ---- PV with raw scores, float4 over d (normalized at consumption next step) ----
  {
    const int dq = tid & 63, tg = tid >> 6;       // 4 t-octets x 64 d-quads
    const float4* eb4 = (const float4*)(enc + ((size_t)b*ET + t0)*D) + dq;
    float4 a4 = {0.f, 0.f, 0.f, 0.f};
    if (t0 < L) {
#pragma unroll
      for (int rr = 0; rr < 8; ++rr) {
        const int r = tg*8 + rr;
        const float scv = s_sc[r];
        const float4 ev = eb4[(size_t)r*64];
        a4.x = fmaf(scv, ev.x, a4.x);
        a4.y = fmaf(scv, ev.y, a4.y);
        a4.z = fmaf(scv, ev.z, a4.z);
        a4.w = fmaf(scv, ev.w, a4.w);
      }
    }
    *(float4*)&s_ra[tg][4*dq] = a4;
    __syncthreads();
    if (t0 < L)
      part_n[tile*D + tid] = (s_ra[0][tid] + s_ra[1][tid])
                           + (s_ra[2][tid] + s_ra[3][tid]);
  }
}

// epilogue: normalize+write outputs of the final step
__global__ __launch_bounds__(256) void k_fin(
    const int* __restrict__ elen, const int* __restrict__ olen,
    const float* __restrict__ ws,
    float* __restrict__ out_att, float* __restrict__ out_sc) {
  const int tid = threadIdx.x;
  const int bid = blockIdx.x;
  const int xcd = bid & 7, slot = bid >> 3;
  const int b = ((slot & 3) << 3) | xcd;
  const int tile = slot >> 2;
  const int t0 = tile * 32;
  const int p = DT & 1;   // parity holding step DT-1's published state

  const float* raw_p = ws + PBUF_OFF + (size_t)b*4*PT + (size_t)(p*2)*PT;
  const float* part_p = ws + PART_OFF + ((size_t)b*2 + p)*NT*D;
  const float* S_p = ws + SSUM_OFF + (b*2 + p)*NT;
  const int L = elen[b];
  const int OL = olen[b];

  float z = 0.f;
#pragma unroll
  for (int j = 0; j < NT; ++j) z += S_p[j];
  const float Zinv = 1.f / z;

  if (tile == 0) {
    float usum = 0.f;
#pragma unroll
    for (int j = 0; j < NT; ++j) usum += part_p[j*D + tid];
    float dmp = (DT-1 < OL) ? 1.f : 0.f;
    out_att[((size_t)b*DT + DT-1)*D + tid] = usum * Zinv * dmp;
  }
  if (tid < 32) {
    const int t = t0 + tid;
    float rv = raw_p[PAD + t];
    out_sc[((size_t)b*DT + DT-1)*ET + t] = (t < L) ? rv * Zinv : 0.f;
  }
}

extern "C" void kernel_launch(void* const* d_in, const int* in_sizes, int n_in,
                              void* d_out, int out_size, void* d_ws, size_t ws_size,
                              hipStream_t stream) {
  const float* enc = (const float*)d_in[0];
  const float* mel = (const float*)d_in[1];
  const int* elen  = (const int*)d_in[2];
  const int* olen  = (const int*)d_in[3];
  const float* vw  = (const float*)d_in[4];   // [1, D]
  const float* W   = (const float*)d_in[5];   // [D, 2, KW]

  float* out_att = (float*)d_out;                 // [B, DT, D]
  float* out_sc  = out_att + (size_t)B*DT*D;      // [B, DT, ET]
  float* ws = (float*)d_ws;

  k_init<<<128, 256, 0, stream>>>(W, ws);
  for (int step = 0; step < DT; ++step)
    k_step<<<1024, 256, 0, stream>>>(enc, mel, elen, olen, vw, ws,
                                     out_att, out_sc, step);
  k_fin<<<1024, 256, 0, stream>>>(elen, olen, ws, out_att, out_sc);
}